// Round 7
// baseline (283.555 us; speedup 1.0000x reference)
//
#include <hip/hip_runtime.h>
#include <hip/hip_cooperative_groups.h>
#include <stdint.h>

namespace cg = cooperative_groups;

// MultiBoxLoss B=16, P=43008, G=128.
// R20: prep collapse. All sort-prep (zeroing, cell hist, scan, scatter,
//      run-bbox + 128-bit GT masks) fused into ONE cooperative kernel
//      k_prep (P/256 blocks x 256, 5 phases via grid.sync) — replaces
//      memset + 4 small kernels whose serialized bodies+drains cost ~45us
//      (R19 ledger). k_mm reverted to PPI=4 (R18 config, faster than
//      PPI=2) with conf gathered via sid (no pconf). k_tail2 unchanged.
//      3 dispatches: k_prep (cooperative), k_mm, k_tail2.

#define GC 8     // GTs per bp-role block
#define PPI 4    // priors/thread in iou role (1024-prior tiles)
#define NCELL 1024  // 16x16 cells x 4 size buckets

__device__ __forceinline__ float sl1(float x) {
  float a = fabsf(x);
  return a < 1.f ? 0.5f * a * a : a - 0.5f;
}

__device__ __forceinline__ double dwave(double v) {
#pragma unroll
  for (int o = 32; o; o >>= 1) v += __shfl_down(v, o);
  return v;
}

__device__ __forceinline__ int cellOf(float4 pr) {
  int cx = (int)(pr.x * 16.f); cx = cx < 0 ? 0 : (cx > 15 ? 15 : cx);
  int cy = (int)(pr.y * 16.f); cy = cy < 0 ? 0 : (cy > 15 ? 15 : cy);
  return ((cy * 16 + cx) << 2) | ((pr.z > 0.17f) ? 2 : 0) |
         ((pr.w > 0.17f) ? 1 : 0);
}

// block-wide inclusive suffix scan over 1024 u32 (one per thread).
__device__ __forceinline__ unsigned bsufscan(unsigned x, unsigned* S,
                                             unsigned* wt, int tid) {
  int lane = tid & 63, wid = tid >> 6;
  unsigned v = x;
#pragma unroll
  for (int o = 1; o < 64; o <<= 1) {
    unsigned u = __shfl_down(v, o);
    if (lane + o < 64) v += u;
  }
  if (lane == 0) wt[wid] = v;
  __syncthreads();
  if (wid == 0) {
    unsigned tv = (lane < 16) ? wt[lane] : 0;
#pragma unroll
    for (int o = 1; o < 16; o <<= 1) {
      unsigned u = __shfl_down(tv, o);
      if (lane + o < 64) tv += u;
    }
    if (lane < 16) wt[lane] = tv;
  }
  __syncthreads();
  unsigned Sv = v + ((wid < 15) ? wt[wid + 1] : 0u);
  S[tid] = Sv;
  __syncthreads();
  return Sv;
}

// ---- fused prep: zero + hist + scan + scatter + run-bbox/GT-masks ----
__global__ __launch_bounds__(256) void k_prep(
    const float* __restrict__ priors, const float* __restrict__ targets,
    float4* __restrict__ spr, unsigned* __restrict__ sid,
    unsigned* __restrict__ inv, uint4* __restrict__ gmask,
    unsigned* __restrict__ cellh, unsigned* __restrict__ cellcur,
    unsigned* __restrict__ zbase, int zwords, int P, int G, int NRW, int B) {
  cg::grid_group grid = cg::this_grid();
  __shared__ unsigned wsum[4];
  int tid = threadIdx.x;
  int gid = blockIdx.x * 256 + tid;
  int total = gridDim.x * 256;

  // phase Z: zero bp/ghist/gacc/gnp/done + cellh
  for (int i = gid; i < zwords; i += total) zbase[i] = 0u;
  for (int i = gid; i < NCELL; i += total) cellh[i] = 0u;
  grid.sync();

  // phase H: cell histogram
  if (gid < P) {
    float4 pr = ((const float4*)priors)[gid];
    atomicAdd(&cellh[cellOf(pr)], 1u);
  }
  grid.sync();

  // phase S: exclusive prefix over 1024 bins (block 0, 4 bins/thread)
  if (blockIdx.x == 0) {
    int lane = tid & 63, wv = tid >> 6;
    unsigned v0 = cellh[tid * 4 + 0], v1 = cellh[tid * 4 + 1];
    unsigned v2 = cellh[tid * 4 + 2], v3 = cellh[tid * 4 + 3];
    unsigned tot = v0 + v1 + v2 + v3;
    unsigned x = tot;
#pragma unroll
    for (int o = 1; o < 64; o <<= 1) {
      unsigned u = __shfl_up(x, o);
      if (lane >= o) x += u;
    }
    if (lane == 63) wsum[wv] = x;
    __syncthreads();
    unsigned base = 0;
    for (int j = 0; j < wv; ++j) base += wsum[j];
    unsigned exc = base + x - tot;
    cellcur[tid * 4 + 0] = exc;
    cellcur[tid * 4 + 1] = exc + v0;
    cellcur[tid * 4 + 2] = exc + v0 + v1;
    cellcur[tid * 4 + 3] = exc + v0 + v1 + v2;
  }
  grid.sync();

  // phase SC: scatter into sorted order
  if (gid < P) {
    float4 pr = ((const float4*)priors)[gid];
    unsigned pos = atomicAdd(&cellcur[cellOf(pr)], 1u);
    spr[pos] = pr;
    sid[pos] = (unsigned)gid;
    inv[gid] = pos;
  }
  grid.sync();

  // phase W: per-run bbox + per-(b,run) 128-bit GT overlap mask
  {
    int wv = tid >> 6, lane = tid & 63;
    for (int run = blockIdx.x * 4 + wv; run < NRW; run += gridDim.x * 4) {
      int p = run * 64 + lane;
      float x1 = 1e30f, y1 = 1e30f, x2 = -1e30f, y2 = -1e30f;
      if (p < P) {
        float4 pr = spr[p];
        x1 = pr.x - pr.z * 0.5f; y1 = pr.y - pr.w * 0.5f;
        x2 = pr.x + pr.z * 0.5f; y2 = pr.y + pr.w * 0.5f;
      }
#pragma unroll
      for (int o = 32; o; o >>= 1) {
        x1 = fminf(x1, __shfl_down(x1, o));
        y1 = fminf(y1, __shfl_down(y1, o));
        x2 = fmaxf(x2, __shfl_down(x2, o));
        y2 = fmaxf(y2, __shfl_down(y2, o));
      }
      x1 = __shfl(x1, 0); y1 = __shfl(y1, 0);
      x2 = __shfl(x2, 0); y2 = __shfl(y2, 0);
      for (int b = 0; b < B; ++b) {
        const float* t0 = targets + ((size_t)b * G + lane) * 15;
        const float* t1 = targets + ((size_t)b * G + lane + 64) * 15;
        bool o0 = (t0[0] < x2) && (x1 < t0[2]) && (t0[1] < y2) && (y1 < t0[3]);
        bool o1 = (t1[0] < x2) && (x1 < t1[2]) && (t1[1] < y2) && (y1 < t1[3]);
        unsigned long long b0 = __ballot(o0);
        unsigned long long b1 = __ballot(o1);
        if (lane == 0)
          gmask[(size_t)b * NRW + run] =
              make_uint4((unsigned)b0, (unsigned)(b0 >> 32), (unsigned)b1,
                         (unsigned)(b1 >> 32));
      }
    }
  }
}

__global__ __launch_bounds__(256) void k_mm(
    const float4* __restrict__ spr, const unsigned* __restrict__ sid,
    const uint4* __restrict__ gmask, const float* __restrict__ conf,
    const float* __restrict__ targets, const float* __restrict__ loc,
    const float* __restrict__ lm, uint2* __restrict__ ovti,
    unsigned long long* __restrict__ bp, float* __restrict__ mine,
    unsigned* __restrict__ ghist, double* __restrict__ pll,
    double* __restrict__ pllm, double* __restrict__ plc,
    double* __restrict__ msum, int* __restrict__ pnp, int P, int G, int NIOU,
    int PTI, int NGC, int PC, int NRW) {
  int tid = threadIdx.x;
  __shared__ char smem[16384];  // bp: sred(16KB); iou: st+rs+ri+hist+smask
  __shared__ float4 sgt[128];
  __shared__ float sga[128];    // bp role reuses as byte-mask store

  if ((int)blockIdx.x < NIOU) {
    // ---- iou role: best-truth per sorted prior + fused loss (sorted) ----
    float* st = (float*)smem;                   // 128*15 floats
    double* rs = (double*)(smem + 7680);        // 16 doubles
    int* ri = (int*)(smem + 7808);              // 4 ints
    unsigned* hist = (unsigned*)(smem + 8192);  // 1024 u32
    unsigned* smaskw = (unsigned*)(smem + 12288);  // 16 runs x uint4 = 64 u32
    int b = blockIdx.x / PTI, tile = blockIdx.x % PTI;
    int base = tile * (256 * PPI);
    for (int i = tid; i < G * 15; i += 256)
      st[i] = targets[(size_t)b * G * 15 + i];
    for (int g = tid; g < G; g += 256) {
      const float* t = targets + ((size_t)b * G + g) * 15;
      float x1 = t[0], y1 = t[1], x2 = t[2], y2 = t[3];
      sgt[g] = make_float4(x1, y1, x2, y2);
      sga[g] = (x2 - x1) * (y2 - y1);
    }
    for (int i = tid; i < 1024; i += 256) hist[i] = 0;
    if (tid < 4 * PPI * 4)
      smaskw[tid] =
          ((const unsigned*)(gmask + (size_t)b * NRW + tile * (4 * PPI)))[tid];
    __syncthreads();

    float px1[PPI], py1[PPI], px2[PPI], py2[PPI], pa[PPI];
    float bi[PPI], sb[PPI];
    int bidx[PPI];
#pragma unroll
    for (int k = 0; k < PPI; ++k) {
      int p = base + tid + k * 256;
      int pl = p < P ? p : P - 1;
      float4 pr = spr[pl];
      px1[k] = pr.x - pr.z * 0.5f; py1[k] = pr.y - pr.w * 0.5f;
      px2[k] = pr.x + pr.z * 0.5f; py2[k] = pr.y + pr.w * 0.5f;
      pa[k] = pr.z * pr.w;
      bi[k] = 0.f; sb[k] = 1.f; bidx[k] = 0;
    }

#define IOU_UPD(GG)                                                        \
  {                                                                        \
    float iw = fminf(T.z, px2[k]) - fmaxf(T.x, px1[k]);                    \
    float ih = fminf(T.w, py2[k]) - fmaxf(T.y, py1[k]);                    \
    float inter = fmaxf(iw, 0.f) * ih;                                     \
    float S = A + pa[k];                                                   \
    if (inter * sb[k] > bi[k] * S) { bi[k] = inter; sb[k] = S; bidx[k] = (GG); } \
  }
#pragma unroll
    for (int k = 0; k < PPI; ++k) {
      int runl = k * 4 + (tid >> 6);
      unsigned mw0 = smaskw[runl * 4 + 0], mw1 = smaskw[runl * 4 + 1];
      unsigned mw2 = smaskw[runl * 4 + 2], mw3 = smaskw[runl * 4 + 3];
      unsigned long long m0 =
          ((unsigned long long)(unsigned)__builtin_amdgcn_readfirstlane(
               (int)mw1)
           << 32) |
          (unsigned)__builtin_amdgcn_readfirstlane((int)mw0);
      unsigned long long m1 =
          ((unsigned long long)(unsigned)__builtin_amdgcn_readfirstlane(
               (int)mw3)
           << 32) |
          (unsigned)__builtin_amdgcn_readfirstlane((int)mw2);
      while (m0) {
        int g = __builtin_ctzll(m0);
        m0 &= m0 - 1;
        float4 T = sgt[g];
        float A = sga[g];
        IOU_UPD(g)
      }
      while (m1) {
        int g = 64 + __builtin_ctzll(m1);
        m1 &= m1 - 1;
        float4 T = sgt[g];
        float A = sga[g];
        IOU_UPD(g)
      }
    }
#undef IOU_UPD

    // ---- fused loss phase, fully in SORTED space (conf gathered) ----
    double ll = 0, llm = 0, lc = 0, ms = 0;
    int np = 0;
#pragma unroll
    for (int k = 0; k < PPI; ++k) {
      int p = base + tid + k * 256;
      if (p < P) {
        size_t idxs = (size_t)b * P + p;
        float ov = bi[k] / (sb[k] - bi[k]);
        int ti = bidx[k];
        ovti[idxs] = make_uint2(__float_as_uint(ov), (unsigned)ti);
        bool pos = ov >= 0.35f;
        unsigned op = sid[p];                    // coalesced
        size_t idxo = (size_t)b * P + op;
        float2 c = ((const float2*)conf)[idxo];  // the 8B gather
        float mx = fmaxf(c.x, c.y);
        float dd = fabsf(c.x - c.y);
        float lse = mx + logf(1.f + expf(-dd));
        float ce = lse - (pos ? c.y : c.x);
        float mv = pos ? 0.f : ce;
        mine[idxs] = mv;
        atomicAdd(&hist[__float_as_uint(mv) >> 21], 1u);
        ms += (double)mv;
        if (pos) {
          np++;
          lc += (double)ce;
          float4 pr = spr[p];
          const float* t = st + ti * 15;
          float rz = 1.f / pr.z, rw = 1.f / pr.w;
          float rdx = 10.f * rz, rdy = 10.f * rw;
          float gx = ((t[0] + t[2]) * 0.5f - pr.x) * rdx;
          float gy = ((t[1] + t[3]) * 0.5f - pr.y) * rdy;
          float gw = logf((t[2] - t[0]) * rz) * 5.0f;
          float gh = logf((t[3] - t[1]) * rw) * 5.0f;
          float4 ld = ((const float4*)loc)[idxo];
          ll += (double)(sl1(ld.x - gx) + sl1(ld.y - gy) + sl1(ld.z - gw) +
                         sl1(ld.w - gh));
          const float2* lmd = (const float2*)lm + idxo * 5;
          float s = 0.f;
#pragma unroll
          for (int j = 0; j < 5; ++j) {
            float2 lv = lmd[j];
            float ex = (t[4 + 2 * j] - pr.x) * rdx;
            float ey = (t[5 + 2 * j] - pr.y) * rdy;
            s += sl1(lv.x - ex) + sl1(lv.y - ey);
          }
          llm += (double)s;
        }
      }
    }

    ll = dwave(ll); llm = dwave(llm); lc = dwave(lc); ms = dwave(ms);
#pragma unroll
    for (int o = 32; o; o >>= 1) np += __shfl_down(np, o);
    int lane = tid & 63, wid = tid >> 6;
    if (lane == 0) {
      rs[wid] = ll; rs[4 + wid] = llm; rs[8 + wid] = lc; rs[12 + wid] = ms;
      ri[wid] = np;
    }
    __syncthreads();
    if (tid == 0) {
      pll[blockIdx.x] = rs[0] + rs[1] + rs[2] + rs[3];
      pllm[blockIdx.x] = rs[4] + rs[5] + rs[6] + rs[7];
      plc[blockIdx.x] = rs[8] + rs[9] + rs[10] + rs[11];
      msum[blockIdx.x] = rs[12] + rs[13] + rs[14] + rs[15];
      pnp[blockIdx.x] = ri[0] + ri[1] + ri[2] + ri[3];
    }
    for (int i = tid; i < 1024; i += 256) {
      unsigned c = hist[i];
      if (c) atomicAdd(&ghist[b * 1024 + i], c);
    }
  } else {
    // ---- bp role: per-GT best-prior, dense structure + byte-mask skips ----
    unsigned long long* sred = (unsigned long long*)smem;  // GC*256
    unsigned char* bm = (unsigned char*)sga;               // run byte masks
    int bc = blockIdx.x - NIOU;
    int pc = bc % PC;
    int gcb = (bc / PC) % NGC;
    int b = bc / (PC * NGC);
    int g0 = gcb * GC;

    int chunk = (P + PC - 1) / PC;
    int ps = pc * chunk;
    int pe = ps + chunk; if (pe > P) pe = P;
    int count = pe - ps;
    int nrun = (count + 63) >> 6;

    if (tid < GC) {
      int g = g0 + tid;
      float4 v = make_float4(0.f, 0.f, 0.f, 0.f);
      if (g < G) {
        const float* t = targets + ((size_t)b * G + g) * 15;
        v = make_float4(t[0], t[1], t[2], t[3]);
      }
      sgt[tid] = v;
    }
    if (tid < nrun) {
      uint4 m = gmask[(size_t)b * NRW + (ps >> 6) + tid];
      unsigned word = (g0 & 64) ? ((g0 & 32) ? m.w : m.z)
                                : ((g0 & 32) ? m.y : m.x);
      bm[tid] = (unsigned char)((word >> (g0 & 31)) & 0xffu);
    }
    __syncthreads();

    float gx1[GC], gy1[GC], gx2[GC], gy2[GC], ga[GC];
#pragma unroll
    for (int j = 0; j < GC; ++j) {
      float4 T = sgt[j];
      gx1[j] = T.x; gy1[j] = T.y; gx2[j] = T.z; gy2[j] = T.w;
      ga[j] = (T.z - T.x) * (T.w - T.y);
    }

    float bi[GC], sb[GC];
    unsigned bpp[GC];
#pragma unroll
    for (int j = 0; j < GC; ++j) { bi[j] = 0.f; sb[j] = 1.f; bpp[j] = 0xFFFFFFFFu; }

#define BP_BODY(X1, Y1, X2, Y2, AR, PP)                                     \
  {                                                                         \
    float iw = fminf(gx2[j], X2) - fmaxf(gx1[j], X1);                       \
    float ih = fminf(gy2[j], Y2) - fmaxf(gy1[j], Y1);                       \
    float inter = fmaxf(iw, 0.f) * ih;                                      \
    float S = ga[j] + AR;                                                   \
    if (inter * sb[j] > bi[j] * S) { bi[j] = inter; sb[j] = S; bpp[j] = (PP); } \
  }
    for (int i = tid; i < count; i += 1024) {
      int ib = __builtin_amdgcn_readfirstlane(i);
      int rl = ib >> 6;
      int i1 = i + 256, i2 = i + 512, i3 = i + 768;
      int p0 = ps + i;
      int p1 = (i1 < count) ? ps + i1 : p0;
      int p2 = (i2 < count) ? ps + i2 : p0;
      int p3 = (i3 < count) ? ps + i3 : p0;
      unsigned by0 = bm[rl];
      unsigned by1 = bm[(ib + 256 < count) ? rl + 4 : rl];
      unsigned by2 = bm[(ib + 512 < count) ? rl + 8 : rl];
      unsigned by3 = bm[(ib + 768 < count) ? rl + 12 : rl];
      by0 = (unsigned)__builtin_amdgcn_readfirstlane((int)by0);
      by1 = (unsigned)__builtin_amdgcn_readfirstlane((int)by1);
      by2 = (unsigned)__builtin_amdgcn_readfirstlane((int)by2);
      by3 = (unsigned)__builtin_amdgcn_readfirstlane((int)by3);
      float4 q0 = spr[p0];
      float4 q1 = spr[p1];
      float4 q2 = spr[p2];
      float4 q3 = spr[p3];
      unsigned s0 = sid[p0], s1 = sid[p1], s2 = sid[p2], s3 = sid[p3];
      float ax1 = q0.x - q0.z * 0.5f, ay1 = q0.y - q0.w * 0.5f;
      float ax2 = q0.x + q0.z * 0.5f, ay2 = q0.y + q0.w * 0.5f;
      float aa = q0.z * q0.w;
      float bx1 = q1.x - q1.z * 0.5f, by1f = q1.y - q1.w * 0.5f;
      float bx2 = q1.x + q1.z * 0.5f, by2f = q1.y + q1.w * 0.5f;
      float ba = q1.z * q1.w;
      float cx1 = q2.x - q2.z * 0.5f, cy1 = q2.y - q2.w * 0.5f;
      float cx2 = q2.x + q2.z * 0.5f, cy2 = q2.y + q2.w * 0.5f;
      float ca = q2.z * q2.w;
      float dx1 = q3.x - q3.z * 0.5f, dy1 = q3.y - q3.w * 0.5f;
      float dx2 = q3.x + q3.z * 0.5f, dy2 = q3.y + q3.w * 0.5f;
      float da = q3.z * q3.w;
#pragma unroll
      for (int j = 0; j < GC; ++j) {
        if (by0 & (1u << j)) BP_BODY(ax1, ay1, ax2, ay2, aa, s0)
        if (by1 & (1u << j)) BP_BODY(bx1, by1f, bx2, by2f, ba, s1)
        if (by2 & (1u << j)) BP_BODY(cx1, cy1, cx2, cy2, ca, s2)
        if (by3 & (1u << j)) BP_BODY(dx1, dy1, dx2, dy2, da, s3)
      }
    }
#undef BP_BODY

#pragma unroll
    for (int j = 0; j < GC; ++j) {
      float iou = bi[j] / (sb[j] - bi[j]);
      unsigned long long pk =
          ((unsigned long long)__float_as_uint(iou) << 32) | (unsigned)(~bpp[j]);
      sred[j * 256 + tid] = pk;
    }
    __syncthreads();
    {
      int j = tid >> 5, s = tid & 31;
      unsigned long long m = sred[j * 256 + s];
#pragma unroll
      for (int t = 1; t < 8; ++t) {
        unsigned long long v = sred[j * 256 + s + t * 32];
        if (v > m) m = v;
      }
      __syncthreads();
      sred[j * 256 + s] = m;
    }
    __syncthreads();
    if (tid < GC) {
      unsigned long long m = sred[tid * 256];
      for (int s = 1; s < 32; ++s) {
        unsigned long long v = sred[tid * 256 + s];
        if (v > m) m = v;
      }
      int g = g0 + tid;
      if (g < G) atomicMax(&bp[(size_t)b * G + g], m);
    }
  }
}

// merged tail: fixup + reduce + select + compact + radix + final fold.
__global__ __launch_bounds__(1024) void k_tail2(
    const unsigned long long* __restrict__ bp, const unsigned* __restrict__ inv,
    uint2* __restrict__ ovti, const float* __restrict__ conf,
    const float* __restrict__ loc, const float* __restrict__ lm,
    const float* __restrict__ priors, const float* __restrict__ targets,
    float* __restrict__ mine, unsigned* __restrict__ ghist,
    const int* __restrict__ pnp, const double* __restrict__ msum,
    const double* __restrict__ pll, const double* __restrict__ pllm,
    const double* __restrict__ plc, double* __restrict__ gacc,
    int* __restrict__ gnp, unsigned* __restrict__ done,
    float* __restrict__ out, int P, int G, int PTI, int B) {
  int b = blockIdx.x, tid = threadIdx.x;
  int lane = tid & 63, wid = tid >> 6;
  __shared__ unsigned spp[128];
  __shared__ double rs[16 * 5];
  __shared__ int ris[16];
  __shared__ unsigned S[1024];
  __shared__ unsigned hs[2048];
  __shared__ unsigned wt[16];
  __shared__ double sdel[4];
  __shared__ int sdnp, sav, smode;
  __shared__ long long sk;
  __shared__ double sA, sC, sD;
  __shared__ int snpos;
  __shared__ int st_, sk1_;
  __shared__ unsigned lcnt;
  __shared__ int spf21, sk2;
  __shared__ unsigned stb;
  __shared__ double stie;

  // ---- part 1: forced-entry fixup (threads 0..G-1) ----
  double dll = 0, dllm = 0, dlc = 0, dms = 0;
  int dnp = 0;
  unsigned pp = 0;
  bool valid = false;
  if (tid < G) {
    unsigned long long m = bp[(size_t)b * G + tid];
    pp = (m == 0ull) ? 0u : ~(unsigned)m;  // sentinel -> prior 0
    float val = __uint_as_float((unsigned)(m >> 32));
    spp[tid] = pp;
    valid = val >= 0.2f;
  }
  int av = __syncthreads_or((tid < G && valid) ? 1 : 0);
  bool win = false;
  if (tid < G) {
    win = true;
    for (int g2 = tid + 1; g2 < G; ++g2)
      if (spp[g2] == pp) { win = false; break; }
  }
  if (win) {
    size_t idx = (size_t)b * P + pp;        // original-order inputs
    unsigned sp = inv[pp];
    size_t idxs = (size_t)b * P + sp;       // sorted-order ovti/mine
    uint2 ot = ovti[idxs];
    float ov_o = __uint_as_float(ot.x);
    int ti_o = (int)ot.y;
    float ov_n = valid ? 2.0f : ov_o;
    int ti_n = tid;
    bool pos_o = ov_o >= 0.35f, pos_n = ov_n >= 0.35f;

    float2 c = ((const float2*)conf)[idx];
    float mx = fmaxf(c.x, c.y);
    float dd = fabsf(c.x - c.y);
    float lse = mx + logf(1.f + expf(-dd));
    float ce_o = lse - (pos_o ? c.y : c.x);
    float ce_n = lse - (pos_n ? c.y : c.x);
    float mv_o = mine[idxs];
    float mv_n = pos_n ? 0.f : ce_n;
    if (mv_n != mv_o) {
      mine[idxs] = mv_n;
      atomicSub(&ghist[b * 1024 + (__float_as_uint(mv_o) >> 21)], 1u);
      atomicAdd(&ghist[b * 1024 + (__float_as_uint(mv_n) >> 21)], 1u);
    }
    dms = (double)mv_n - (double)mv_o;
    dnp = (pos_n ? 1 : 0) - (pos_o ? 1 : 0);
    dlc = (pos_n ? (double)ce_n : 0.0) - (pos_o ? (double)ce_o : 0.0);

    if (pos_o || pos_n) {
      float4 pr = ((const float4*)priors)[pp];
      float rz = 1.f / pr.z, rw = 1.f / pr.w;
      float rdx = 10.f * rz, rdy = 10.f * rw;
      float4 ld = ((const float4*)loc)[idx];
      const float2* lmd = (const float2*)lm + idx * 5;
      float2 lv[5];
#pragma unroll
      for (int j = 0; j < 5; ++j) lv[j] = lmd[j];
      for (int pass = 0; pass < 2; ++pass) {
        bool act = pass ? pos_n : pos_o;
        int ti = pass ? ti_n : ti_o;
        if (!act) continue;
        const float* t = targets + ((size_t)b * G + ti) * 15;
        float gx = ((t[0] + t[2]) * 0.5f - pr.x) * rdx;
        float gy = ((t[1] + t[3]) * 0.5f - pr.y) * rdy;
        float gw = logf((t[2] - t[0]) * rz) * 5.0f;
        float gh = logf((t[3] - t[1]) * rw) * 5.0f;
        double l = (double)(sl1(ld.x - gx) + sl1(ld.y - gy) +
                            sl1(ld.z - gw) + sl1(ld.w - gh));
        float s = 0.f;
#pragma unroll
        for (int j = 0; j < 5; ++j) {
          float ex = (t[4 + 2 * j] - pr.x) * rdx;
          float ey = (t[5 + 2 * j] - pr.y) * rdy;
          s += sl1(lv[j].x - ex) + sl1(lv[j].y - ey);
        }
        if (pass) { dll += l; dllm += (double)s; }
        else { dll -= l; dllm -= (double)s; }
      }
    }
  }
  dll = dwave(dll); dllm = dwave(dllm); dlc = dwave(dlc); dms = dwave(dms);
#pragma unroll
  for (int o = 32; o; o >>= 1) dnp += __shfl_down(dnp, o);
  if (lane == 0) {
    rs[wid] = dll; rs[16 + wid] = dllm; rs[32 + wid] = dlc; rs[48 + wid] = dms;
    ris[wid] = dnp;
  }
  __syncthreads();
  if (tid == 0) {
    double a = 0, c2 = 0, d2 = 0, m2 = 0;
    int n2 = 0;
    for (int i = 0; i < 16; ++i) {
      a += rs[i]; c2 += rs[16 + i]; d2 += rs[32 + i]; m2 += rs[48 + i];
      n2 += ris[i];
    }
    sdel[0] = a; sdel[1] = c2; sdel[2] = d2; sdel[3] = m2;
    sdnp = n2; sav = av;
  }
  __syncthreads();

  // ---- part 2: reduce loss-phase partials ----
  double a = 0, cc = 0, d = 0, ms = 0;
  int n = 0;
  for (int i = tid; i < PTI; i += 1024) {
    int ix = b * PTI + i;
    a += pll[ix]; cc += pllm[ix]; d += plc[ix]; ms += msum[ix]; n += pnp[ix];
  }
  a = dwave(a); cc = dwave(cc); d = dwave(d); ms = dwave(ms);
#pragma unroll
  for (int o = 32; o; o >>= 1) n += __shfl_down(n, o);
  if (lane == 0) {
    rs[wid] = a; rs[16 + wid] = cc; rs[32 + wid] = d; rs[48 + wid] = ms;
    ris[wid] = n;
  }
  __syncthreads();
  double Fv = 0.0;  // meaningful on tid 0 only
  if (tid == 0) {
    double A = 0, C = 0, D = 0, MS = 0;
    int npos = 0;
    for (int i = 0; i < 16; ++i) {
      A += rs[i]; C += rs[16 + i]; D += rs[32 + i]; MS += rs[48 + i];
      npos += ris[i];
    }
    A += sdel[0]; C += sdel[1]; D += sdel[2]; MS += sdel[3];
    npos += sdnp;
    if (!sav) { A = 0; C = 0; D = 0; npos = 0; }
    sA = A; sC = C; sD = D; snpos = npos;
    long long k = 7LL * (long long)npos;
    long long cap = P - 1;
    int md = 1;
    if (k <= 0) { Fv = 0.0; md = 0; }
    else if (k >= cap) { Fv = MS; md = 0; }
    smode = md; sk = k;
  }
  __syncthreads();

  if (smode) {
    long long k = sk;
    // ---- part 3: pass-0 select from ghist ----
    {
      unsigned x = ghist[b * 1024 + tid];
      unsigned Sv = bsufscan(x, S, wt, tid);
      int cnt_ = __syncthreads_count((long long)Sv >= k);
      int seg = cnt_ - 1;
      if (tid == seg) {
        long long cum = (seg + 1 < 1024) ? (long long)S[seg + 1] : 0;
        st_ = seg;
        sk1_ = (int)(k - cum);
      }
      if (tid == 0) lcnt = 0;
    }
    __syncthreads();
    int t = st_;
    long long k1 = (long long)sk1_;

    // ---- part 4: sweep mine (4-wide): above-bin sum + compact bin-t ----
    const float* mrow = mine + (size_t)b * P;
    float* crow = (float*)(ovti + (size_t)b * P);  // cbuf aliases ovti row b
    double acc = 0;
    for (int base0 = 0; base0 < P; base0 += 4096) {
#pragma unroll
      for (int j = 0; j < 4; ++j) {
        int p = base0 + tid + j * 1024;
        bool keep = false;
        unsigned bb = 0;
        if (p < P) {
          bb = __float_as_uint(mrow[p]);
          int bin = (int)(bb >> 21);
          if (bin > t) acc += (double)__uint_as_float(bb);
          else keep = (bin == t);
        }
        unsigned long long mk = __ballot(keep);
        int nset = __popcll(mk);
        if (nset) {
          unsigned wbase = 0;
          if (lane == 0) wbase = atomicAdd(&lcnt, (unsigned)nset);
          wbase = __shfl(wbase, 0);
          if (keep) {
            int offi = __popcll(mk & ((1ull << lane) - 1ull));
            crow[wbase + offi] = __uint_as_float(bb);
          }
        }
      }
    }
    acc = dwave(acc);
    if (lane == 0) rs[wid] = acc;
    __syncthreads();
    int nn = (int)lcnt;

    // ---- part 5a: pass A hist (bits[20:10], 2048 bins) over cbuf ----
    hs[tid] = 0; hs[tid + 1024] = 0;
    __syncthreads();
    for (int i = tid; i < nn; i += 1024) {
      unsigned bb = __float_as_uint(crow[i]);
      atomicAdd(&hs[(bb >> 10) & 2047], 1u);
    }
    __syncthreads();
    {
      unsigned h0 = hs[tid * 2], h1v = hs[tid * 2 + 1];
      unsigned Sv = bsufscan(h0 + h1v, S, wt, tid);
      int cnt_ = __syncthreads_count((long long)Sv >= k1);
      int seg = cnt_ - 1;
      if (tid == seg) {
        long long cum = (seg + 1 < 1024) ? (long long)S[seg + 1] : 0;
        int bin = seg * 2;
        if (cum + h1v >= k1) bin = seg * 2 + 1;
        else cum += h1v;
        spf21 = (t << 11) | bin;
        sk2 = (int)(k1 - cum);
      }
    }
    __syncthreads();
    int pf21 = spf21;

    // ---- part 5b: pass B hist (bits[9:0], 1024 bins) ----
    hs[tid] = 0;
    __syncthreads();
    for (int i = tid; i < nn; i += 1024) {
      unsigned bb = __float_as_uint(crow[i]);
      if ((int)(bb >> 10) == pf21) atomicAdd(&hs[bb & 1023], 1u);
    }
    __syncthreads();
    {
      unsigned Sv = bsufscan(hs[tid], S, wt, tid);
      long long kk = (long long)sk2;
      int cnt_ = __syncthreads_count((long long)Sv >= kk);
      int seg = cnt_ - 1;
      if (tid == seg) {
        long long cum = (seg + 1 < 1024) ? (long long)S[seg + 1] : 0;
        unsigned tb = ((unsigned)pf21 << 10) | (unsigned)seg;
        stb = tb;
        stie = (double)(kk - cum) * (double)__uint_as_float(tb);
      }
    }
    __syncthreads();

    // ---- part 5c: final sum over cbuf elems > tb ----
    unsigned tb = stb;
    double v = 0.0;
    for (int i = tid; i < nn; i += 1024) {
      unsigned bb = __float_as_uint(crow[i]);
      if (bb > tb) v += (double)__uint_as_float(bb);
    }
    v = dwave(v);
    if (lane == 0) rs[16 + wid] = v;
    __syncthreads();
    if (tid == 0) {
      double hi = 0, vt = 0;
      for (int i = 0; i < 16; ++i) { hi += rs[i]; vt += rs[16 + i]; }
      Fv = hi + vt + stie;
    }
  }

  // ---- part 6: fold into global accumulators; last block writes out ----
  if (tid == 0) {
    atomicAdd(&gacc[0], sA);
    atomicAdd(&gacc[1], sC);
    atomicAdd(&gacc[2], sD);
    atomicAdd(&gacc[3], Fv);
    atomicAdd(gnp, snpos);
    __threadfence();
    unsigned old = atomicAdd(done, 1u);
    if (old == (unsigned)B - 1) {
      __threadfence();
      double A = atomicAdd(&gacc[0], 0.0);
      double C = atomicAdd(&gacc[1], 0.0);
      double D = atomicAdd(&gacc[2], 0.0);
      double F = atomicAdd(&gacc[3], 0.0);
      int N = atomicAdd(gnp, 0);
      double Nd = N < 1 ? 1.0 : (double)N;
      out[0] = (float)(A / Nd);
      out[1] = (float)((D + F) / Nd);
      out[2] = (float)(C / Nd);
    }
  }
}

extern "C" void kernel_launch(void* const* d_in, const int* in_sizes, int n_in,
                              void* d_out, int out_size, void* d_ws,
                              size_t ws_size, hipStream_t stream) {
  const float* loc = (const float*)d_in[0];
  const float* conf = (const float*)d_in[1];
  const float* lm = (const float*)d_in[2];
  const float* priors = (const float*)d_in[3];
  const float* targets = (const float*)d_in[4];

  int P = in_sizes[3] / 4;
  int B = in_sizes[0] / (4 * P);
  int G = in_sizes[4] / (15 * B);
  int PTI = (P + 256 * PPI - 1) / (256 * PPI);
  int NIOU = B * PTI;
  int NGC = (G + GC - 1) / GC;
  int PC = 8;
  int NBP = B * NGC * PC;
  int NPB = (P + 255) / 256;    // prep blocks (168)
  int NRW = (P + 63) / 64;      // 64-prior runs (P=43008 -> 672, exact)
  int NW = B * NRW;

  char* w = (char*)d_ws;
  size_t off = 0;
  // ---- zeroed-by-k_prep region: bp + ghist + gacc + gnp + done ----
  unsigned long long* bp = (unsigned long long*)(w + off);
  off += (size_t)B * G * 8;
  unsigned* ghist = (unsigned*)(w + off);
  off += (size_t)B * 1024 * 4;
  double* gacc = (double*)(w + off);
  off += 4 * 8;
  int* gnp = (int*)(w + off);
  off += 4;
  unsigned* done = (unsigned*)(w + off);
  off += 4;
  size_t clear_bytes = off;
  // ---- non-zeroed (written unconditionally every call) ----
  off = (off + 255) & ~(size_t)255;
  float4* spr = (float4*)(w + off);
  off += (size_t)NRW * 64 * 16;
  unsigned* sid = (unsigned*)(w + off);
  off += (size_t)P * 4;
  unsigned* inv = (unsigned*)(w + off);
  off += (size_t)P * 4;
  uint4* gmask = (uint4*)(w + off);
  off += (size_t)NW * 16;
  unsigned* cellh = (unsigned*)(w + off);
  off += (size_t)NCELL * 4;
  unsigned* cellcur = (unsigned*)(w + off);
  off += (size_t)NCELL * 4;
  off = (off + 255) & ~(size_t)255;
  uint2* ovti = (uint2*)(w + off);  // rows also reused as cbuf in k_tail2
  off += (size_t)B * P * 8;
  float* mine = (float*)(w + off);
  off += (size_t)B * P * 4;
  double* pll = (double*)(w + off);
  off += (size_t)NIOU * 8;
  double* pllm = (double*)(w + off);
  off += (size_t)NIOU * 8;
  double* plc = (double*)(w + off);
  off += (size_t)NIOU * 8;
  double* msum = (double*)(w + off);
  off += (size_t)NIOU * 8;
  int* pnp = (int*)(w + off);
  off += (size_t)NIOU * 4;

  unsigned* zbase = (unsigned*)w;
  int zwords = (int)(clear_bytes / 4);

  void* pargs[] = {(void*)&priors, (void*)&targets, (void*)&spr, (void*)&sid,
                   (void*)&inv,    (void*)&gmask,   (void*)&cellh,
                   (void*)&cellcur, (void*)&zbase,  (void*)&zwords,
                   (void*)&P,      (void*)&G,       (void*)&NRW, (void*)&B};
  hipLaunchCooperativeKernel((void*)k_prep, dim3(NPB), dim3(256), pargs, 0,
                             stream);

  k_mm<<<NIOU + NBP, 256, 0, stream>>>(spr, sid, gmask, conf, targets, loc,
                                       lm, ovti, bp, mine, ghist, pll, pllm,
                                       plc, msum, pnp, P, G, NIOU, PTI, NGC,
                                       PC, NRW);
  k_tail2<<<B, 1024, 0, stream>>>(bp, inv, ovti, conf, loc, lm, priors,
                                  targets, mine, ghist, pnp, msum, pll, pllm,
                                  plc, gacc, gnp, done, (float*)d_out, P, G,
                                  PTI, B);
}

// Round 8
// 178.178 us; speedup vs baseline: 1.5914x; 1.5914x over previous
//
#include <hip/hip_runtime.h>
#include <stdint.h>

// MultiBoxLoss B=16, P=43008, G=128.
// R21: restore R13 (best-measured 177.1us). Session ledger (R14-R20):
//   - tail parallelization (R14), dispatch collapse (R15): neutral (+-2us).
//   - spatial sort + wave-bbox prune cuts k_mm 85->58.5us (R18) but the
//     sort-prep costs 45+us in kernel bodies; net-negative in ALL configs
//     (R18 197.6, R19 202.5). Cooperative-kernel prep (R20): grid.sync
//     ~25us each -> 283.6. Sort path abandoned.
//   - k_mm is VALU-issue-bound (VALUBusy ~100%, HBM 4%): compute roofline.
//   - ~65us/iter is harness reset (memset storm), unfixable kernel-side.
// R13 structure: k_main eliminated — per-prior loss work fused into k_mm's
// iou role (uses in-register pre-scatter ov/ti; conf/loc/lm read once).
// Forced entries (<=G per b) corrected by k_fix delta kernel (exact doubles,
// identical float paths). anyv==0 handled by gating in k_tail. Slow path
// (never taken in practice) builds its own hist in k_tail.
// 5 dispatches: memset(16KB), k_mm, k_fix, k_tail, k_fin.

#define GC 8    // GTs per bp-role block
#define PPI 4   // priors/thread in iou role

__device__ __forceinline__ float sl1(float x) {
  float a = fabsf(x);
  return a < 1.f ? 0.5f * a * a : a - 0.5f;
}

__device__ __forceinline__ double dwave(double v) {
#pragma unroll
  for (int o = 32; o; o >>= 1) v += __shfl_down(v, o);
  return v;
}

__global__ __launch_bounds__(256) void k_mm(
    const float* __restrict__ priors, const float* __restrict__ targets,
    const float* __restrict__ loc, const float* __restrict__ conf,
    const float* __restrict__ lm, float* __restrict__ bto,
    int* __restrict__ bti, unsigned long long* __restrict__ bp,
    float* __restrict__ mine, double* __restrict__ pll,
    double* __restrict__ pllm, double* __restrict__ plc,
    double* __restrict__ msum, int* __restrict__ pnp, int P, int G, int NIOU,
    int PTI, int NGC, int PC) {
  int tid = threadIdx.x;
  __shared__ char smem[16384];  // bp: sred(16KB); iou: st(7.5KB)+rs+ri
  __shared__ float4 sgt[128];
  __shared__ float sga[128];

  if ((int)blockIdx.x < NIOU) {
    // ---- iou role: best-truth per prior + full per-prior loss work ----
    float* st = (float*)smem;                  // 128*15 floats
    double* rs = (double*)(smem + 7680);       // 16 doubles
    int* ri = (int*)(smem + 7808);             // 4 ints
    int b = blockIdx.x / PTI, tile = blockIdx.x % PTI;
    int base = tile * (256 * PPI);
    for (int i = tid; i < G * 15; i += 256)
      st[i] = targets[(size_t)b * G * 15 + i];
    for (int g = tid; g < G; g += 256) {
      const float* t = targets + ((size_t)b * G + g) * 15;
      float x1 = t[0], y1 = t[1], x2 = t[2], y2 = t[3];
      sgt[g] = make_float4(x1, y1, x2, y2);
      sga[g] = (x2 - x1) * (y2 - y1);
    }
    __syncthreads();

    float px1[PPI], py1[PPI], px2[PPI], py2[PPI], pa[PPI];
    float bi[PPI], sb[PPI];
    int bidx[PPI];
#pragma unroll
    for (int k = 0; k < PPI; ++k) {
      int p = base + tid + k * 256;
      int pl = p < P ? p : P - 1;
      float4 pr = ((const float4*)priors)[pl];
      px1[k] = pr.x - pr.z * 0.5f; py1[k] = pr.y - pr.w * 0.5f;
      px2[k] = pr.x + pr.z * 0.5f; py2[k] = pr.y + pr.w * 0.5f;
      pa[k] = pr.z * pr.w;
      bi[k] = 0.f; sb[k] = 1.f; bidx[k] = 0;
    }

#define IOU_BODY(T, A, GG)                                                 \
  {                                                                        \
    float iw = fminf(T.z, px2[k]) - fmaxf(T.x, px1[k]);                    \
    float ih = fminf(T.w, py2[k]) - fmaxf(T.y, py1[k]);                    \
    float inter = fmaxf(iw, 0.f) * ih;                                     \
    float S = A + pa[k];                                                   \
    if (inter * sb[k] > bi[k] * S) { bi[k] = inter; sb[k] = S; bidx[k] = GG; } \
  }
    for (int g = 0; g < G; g += 4) {
      float4 T0 = sgt[g], T1 = sgt[g + 1], T2 = sgt[g + 2], T3 = sgt[g + 3];
      float A0 = sga[g], A1 = sga[g + 1], A2 = sga[g + 2], A3 = sga[g + 3];
#pragma unroll
      for (int k = 0; k < PPI; ++k) {
        IOU_BODY(T0, A0, g)
        IOU_BODY(T1, A1, g + 1)
        IOU_BODY(T2, A2, g + 2)
        IOU_BODY(T3, A3, g + 3)
      }
    }
#undef IOU_BODY

    // ---- main phase (pre-scatter ov/ti; k_fix corrects forced entries) ----
    double ll = 0, llm = 0, lc = 0, ms = 0;
    int np = 0;
#pragma unroll
    for (int k = 0; k < PPI; ++k) {
      int p = base + tid + k * 256;
      if (p < P) {
        size_t idx = (size_t)b * P + p;
        float ov = bi[k] / (sb[k] - bi[k]);
        int ti = bidx[k];
        bto[idx] = ov;
        bti[idx] = ti;
        bool pos = ov >= 0.35f;
        float2 c = ((const float2*)conf)[idx];
        float mx = fmaxf(c.x, c.y);
        float dd = fabsf(c.x - c.y);
        float lse = mx + logf(1.f + expf(-dd));
        float ce = lse - (pos ? c.y : c.x);
        float mv = pos ? 0.f : ce;
        mine[idx] = mv;
        ms += (double)mv;
        if (pos) {
          np++;
          lc += (double)ce;
          float4 pr = ((const float4*)priors)[p];
          const float* t = st + ti * 15;
          float rz = 1.f / pr.z, rw = 1.f / pr.w;
          float rdx = 10.f * rz, rdy = 10.f * rw;
          float gx = ((t[0] + t[2]) * 0.5f - pr.x) * rdx;
          float gy = ((t[1] + t[3]) * 0.5f - pr.y) * rdy;
          float gw = logf((t[2] - t[0]) * rz) * 5.0f;
          float gh = logf((t[3] - t[1]) * rw) * 5.0f;
          float4 ld = ((const float4*)loc)[idx];
          ll += (double)(sl1(ld.x - gx) + sl1(ld.y - gy) + sl1(ld.z - gw) +
                         sl1(ld.w - gh));
          const float2* lmd = (const float2*)lm + idx * 5;
          float s = 0.f;
#pragma unroll
          for (int j = 0; j < 5; ++j) {
            float2 lv = lmd[j];
            float ex = (t[4 + 2 * j] - pr.x) * rdx;
            float ey = (t[5 + 2 * j] - pr.y) * rdy;
            s += sl1(lv.x - ex) + sl1(lv.y - ey);
          }
          llm += (double)s;
        }
      }
    }

    ll = dwave(ll); llm = dwave(llm); lc = dwave(lc); ms = dwave(ms);
#pragma unroll
    for (int o = 32; o; o >>= 1) np += __shfl_down(np, o);
    int lane = tid & 63, wid = tid >> 6;
    if (lane == 0) {
      rs[wid] = ll; rs[4 + wid] = llm; rs[8 + wid] = lc; rs[12 + wid] = ms;
      ri[wid] = np;
    }
    __syncthreads();
    if (tid == 0) {
      pll[blockIdx.x] = rs[0] + rs[1] + rs[2] + rs[3];
      pllm[blockIdx.x] = rs[4] + rs[5] + rs[6] + rs[7];
      plc[blockIdx.x] = rs[8] + rs[9] + rs[10] + rs[11];
      msum[blockIdx.x] = rs[12] + rs[13] + rs[14] + rs[15];
      pnp[blockIdx.x] = ri[0] + ri[1] + ri[2] + ri[3];
    }
  } else {
    // ---- bp role: per-GT best-prior over a P-chunk ----
    unsigned long long* sred = (unsigned long long*)smem;  // GC*256
    int bc = blockIdx.x - NIOU;
    int pc = bc % PC;
    int gcb = (bc / PC) % NGC;
    int b = bc / (PC * NGC);
    int g0 = gcb * GC;

    if (tid < GC) {
      int g = g0 + tid;
      float4 v = make_float4(0.f, 0.f, 0.f, 0.f);
      if (g < G) {
        const float* t = targets + ((size_t)b * G + g) * 15;
        v = make_float4(t[0], t[1], t[2], t[3]);
      }
      sgt[tid] = v;
    }
    __syncthreads();

    float gx1[GC], gy1[GC], gx2[GC], gy2[GC], ga[GC];
#pragma unroll
    for (int j = 0; j < GC; ++j) {
      float4 T = sgt[j];
      gx1[j] = T.x; gy1[j] = T.y; gx2[j] = T.z; gy2[j] = T.w;
      ga[j] = (T.z - T.x) * (T.w - T.y);
    }

    int chunk = (P + PC - 1) / PC;
    int ps = pc * chunk;
    int pe = ps + chunk; if (pe > P) pe = P;
    int count = pe - ps;

    float bi[GC], sb[GC];
    unsigned bpp[GC];
#pragma unroll
    for (int j = 0; j < GC; ++j) { bi[j] = 0.f; sb[j] = 1.f; bpp[j] = (unsigned)(ps + tid); }

#define BP_BODY(X1, Y1, X2, Y2, AR, PP)                                     \
  {                                                                         \
    float iw = fminf(gx2[j], X2) - fmaxf(gx1[j], X1);                       \
    float ih = fminf(gy2[j], Y2) - fmaxf(gy1[j], Y1);                       \
    float inter = fmaxf(iw, 0.f) * ih;                                      \
    float S = ga[j] + AR;                                                   \
    if (inter * sb[j] > bi[j] * S) { bi[j] = inter; sb[j] = S; bpp[j] = (unsigned)PP; } \
  }
    for (int i = tid; i < count; i += 1024) {
      int p0 = ps + i;
      int i1 = i + 256, i2 = i + 512, i3 = i + 768;
      int p1 = (i1 < count) ? ps + i1 : p0;
      int p2 = (i2 < count) ? ps + i2 : p0;
      int p3 = (i3 < count) ? ps + i3 : p0;
      float4 q0 = ((const float4*)priors)[p0];
      float4 q1 = ((const float4*)priors)[p1];
      float4 q2 = ((const float4*)priors)[p2];
      float4 q3 = ((const float4*)priors)[p3];
      float ax1 = q0.x - q0.z * 0.5f, ay1 = q0.y - q0.w * 0.5f;
      float ax2 = q0.x + q0.z * 0.5f, ay2 = q0.y + q0.w * 0.5f;
      float aa = q0.z * q0.w;
      float bx1 = q1.x - q1.z * 0.5f, by1 = q1.y - q1.w * 0.5f;
      float bx2 = q1.x + q1.z * 0.5f, by2 = q1.y + q1.w * 0.5f;
      float ba = q1.z * q1.w;
      float cx1 = q2.x - q2.z * 0.5f, cy1 = q2.y - q2.w * 0.5f;
      float cx2 = q2.x + q2.z * 0.5f, cy2 = q2.y + q2.w * 0.5f;
      float ca = q2.z * q2.w;
      float dx1 = q3.x - q3.z * 0.5f, dy1 = q3.y - q3.w * 0.5f;
      float dx2 = q3.x + q3.z * 0.5f, dy2 = q3.y + q3.w * 0.5f;
      float da = q3.z * q3.w;
#pragma unroll
      for (int j = 0; j < GC; ++j) {
        BP_BODY(ax1, ay1, ax2, ay2, aa, p0)
        BP_BODY(bx1, by1, bx2, by2, ba, p1)
        BP_BODY(cx1, cy1, cx2, cy2, ca, p2)
        BP_BODY(dx1, dy1, dx2, dy2, da, p3)
      }
    }
#undef BP_BODY

#pragma unroll
    for (int j = 0; j < GC; ++j) {
      float iou = bi[j] / (sb[j] - bi[j]);
      unsigned long long pk =
          ((unsigned long long)__float_as_uint(iou) << 32) | (unsigned)(~bpp[j]);
      sred[j * 256 + tid] = pk;
    }
    __syncthreads();
    {
      int j = tid >> 5, s = tid & 31;
      unsigned long long m = sred[j * 256 + s];
#pragma unroll
      for (int t = 1; t < 8; ++t) {
        unsigned long long v = sred[j * 256 + s + t * 32];
        if (v > m) m = v;
      }
      __syncthreads();
      sred[j * 256 + s] = m;
    }
    __syncthreads();
    if (tid < GC) {
      unsigned long long m = sred[tid * 256];
      for (int s = 1; s < 32; ++s) {
        unsigned long long v = sred[tid * 256 + s];
        if (v > m) m = v;
      }
      int g = g0 + tid;
      if (g < G) atomicMax(&bp[(size_t)b * G + g], m);
    }
  }
}

// per-b fixup of forced entries: last-dup-wins, ti:=g always, ov:=2 iff valid.
// Computes exact delta contributions (identical float paths as k_mm).
__global__ void k_fix(const unsigned long long* __restrict__ bp,
                      const float* __restrict__ bto, const int* __restrict__ bti,
                      const float* __restrict__ conf, const float* __restrict__ loc,
                      const float* __restrict__ lm, const float* __restrict__ priors,
                      const float* __restrict__ targets, float* __restrict__ mine,
                      int* __restrict__ anyv, double* __restrict__ dacc,
                      int* __restrict__ dnpb, int P, int G) {
  int b = blockIdx.x, g = threadIdx.x;
  __shared__ unsigned spp[128];
  __shared__ double sd[128 * 4];
  __shared__ int si[128];

  unsigned long long m = bp[(size_t)b * G + g];
  unsigned pp = ~(unsigned)m;
  float val = __uint_as_float((unsigned)(m >> 32));
  spp[g] = pp;
  bool valid = val >= 0.2f;
  int av = __syncthreads_or(valid ? 1 : 0);
  if (g == 0) anyv[b] = av;

  bool win = true;
  for (int g2 = g + 1; g2 < G; ++g2)
    if (spp[g2] == pp) { win = false; break; }

  double dll = 0, dllm = 0, dlc = 0, dms = 0;
  int dnp = 0;
  if (win) {
    size_t idx = (size_t)b * P + pp;
    float ov_o = bto[idx];
    int ti_o = bti[idx];
    float ov_n = valid ? 2.0f : ov_o;
    int ti_n = g;
    bool pos_o = ov_o >= 0.35f, pos_n = ov_n >= 0.35f;

    float2 c = ((const float2*)conf)[idx];
    float mx = fmaxf(c.x, c.y);
    float dd = fabsf(c.x - c.y);
    float lse = mx + logf(1.f + expf(-dd));
    float ce_o = lse - (pos_o ? c.y : c.x);
    float ce_n = lse - (pos_n ? c.y : c.x);
    float mv_o = mine[idx];
    float mv_n = pos_n ? 0.f : ce_n;
    if (mv_n != mv_o) mine[idx] = mv_n;
    dms = (double)mv_n - (double)mv_o;
    dnp = (pos_n ? 1 : 0) - (pos_o ? 1 : 0);
    dlc = (pos_n ? (double)ce_n : 0.0) - (pos_o ? (double)ce_o : 0.0);

    if (pos_o || pos_n) {
      float4 pr = ((const float4*)priors)[pp];
      float rz = 1.f / pr.z, rw = 1.f / pr.w;
      float rdx = 10.f * rz, rdy = 10.f * rw;
      float4 ld = ((const float4*)loc)[idx];
      const float2* lmd = (const float2*)lm + idx * 5;
      float2 lv[5];
#pragma unroll
      for (int j = 0; j < 5; ++j) lv[j] = lmd[j];
      for (int pass = 0; pass < 2; ++pass) {
        bool act = pass ? pos_n : pos_o;
        int ti = pass ? ti_n : ti_o;
        if (!act) continue;
        const float* t = targets + ((size_t)b * G + ti) * 15;
        float gx = ((t[0] + t[2]) * 0.5f - pr.x) * rdx;
        float gy = ((t[1] + t[3]) * 0.5f - pr.y) * rdy;
        float gw = logf((t[2] - t[0]) * rz) * 5.0f;
        float gh = logf((t[3] - t[1]) * rw) * 5.0f;
        double l = (double)(sl1(ld.x - gx) + sl1(ld.y - gy) +
                            sl1(ld.z - gw) + sl1(ld.w - gh));
        float s = 0.f;
#pragma unroll
        for (int j = 0; j < 5; ++j) {
          float ex = (t[4 + 2 * j] - pr.x) * rdx;
          float ey = (t[5 + 2 * j] - pr.y) * rdy;
          s += sl1(lv[j].x - ex) + sl1(lv[j].y - ey);
        }
        if (pass) { dll += l; dllm += (double)s; }
        else { dll -= l; dllm -= (double)s; }
      }
    }
  }
  sd[g] = dll; sd[128 + g] = dllm; sd[256 + g] = dlc; sd[384 + g] = dms;
  si[g] = dnp;
  __syncthreads();
  for (int off = 64; off; off >>= 1) {
    if (g < off) {
      sd[g] += sd[g + off]; sd[128 + g] += sd[128 + g + off];
      sd[256 + g] += sd[256 + g + off]; sd[384 + g] += sd[384 + g + off];
      si[g] += si[g + off];
    }
    __syncthreads();
  }
  if (g == 0) {
    dacc[b * 4 + 0] = sd[0]; dacc[b * 4 + 1] = sd[128];
    dacc[b * 4 + 2] = sd[256]; dacc[b * 4 + 3] = sd[384];
    dnpb[b] = si[0];
  }
}

// per-b tail: reduce partials + deltas, gate by anyv, fast/slow path.
__global__ __launch_bounds__(1024) void k_tail(
    const int* __restrict__ pnp, const double* __restrict__ msum,
    const double* __restrict__ pll, const double* __restrict__ pllm,
    const double* __restrict__ plc, const double* __restrict__ dacc,
    const int* __restrict__ dnpb, const int* __restrict__ anyv,
    const float* __restrict__ mine, int* __restrict__ num_pos,
    double* __restrict__ pllb, double* __restrict__ pllmb,
    double* __restrict__ plcb, double* __restrict__ pfs_b, int P, int PTI) {
  int b = blockIdx.x, tid = threadIdx.x;
  __shared__ double rs[16 * 5];
  __shared__ int ris[16];
  __shared__ unsigned S[1024];
  __shared__ unsigned hs[2048];
  __shared__ int spf1, sk1, spf21, sk2;
  __shared__ unsigned stb;
  __shared__ double stie;

  double a = 0, cc = 0, d = 0, ms = 0;
  int n = 0;
  for (int i = tid; i < PTI; i += 1024) {
    int ix = b * PTI + i;
    a += pll[ix]; cc += pllm[ix]; d += plc[ix]; ms += msum[ix]; n += pnp[ix];
  }
  a = dwave(a); cc = dwave(cc); d = dwave(d); ms = dwave(ms);
#pragma unroll
  for (int o = 32; o; o >>= 1) n += __shfl_down(n, o);
  int lane = tid & 63, wid = tid >> 6;
  if (lane == 0) {
    rs[wid] = a; rs[16 + wid] = cc; rs[32 + wid] = d; rs[48 + wid] = ms;
    ris[wid] = n;
  }
  __syncthreads();
  int npos = 0;
  double A = 0, C = 0, D = 0, MS = 0;
  if (tid == 0) {
    for (int i = 0; i < 16; ++i) {
      A += rs[i]; C += rs[16 + i]; D += rs[32 + i]; MS += rs[48 + i];
      npos += ris[i];
    }
    A += dacc[b * 4 + 0]; C += dacc[b * 4 + 1]; D += dacc[b * 4 + 2];
    MS += dacc[b * 4 + 3];
    npos += dnpb[b];
    if (!anyv[b]) { A = 0; C = 0; D = 0; npos = 0; }
    num_pos[b] = npos;
    pllb[b] = A; pllmb[b] = C; plcb[b] = D;
    ris[0] = npos;
    rs[48] = MS;  // reuse slot for gated decision below
  }
  __syncthreads();
  npos = ris[0];
  MS = rs[48];

  long long k = 7LL * (long long)npos;
  long long cap = P - 1;
  if (k <= 0) {
    if (tid == 0) pfs_b[b] = 0.0;
    return;
  }
  if (k >= cap) {
    if (tid == 0) pfs_b[b] = MS;  // FAST PATH: all negatives selected
    return;
  }

  const float* mrow = mine + (size_t)b * P;
  // pass 0: hist over bits[31:21] (mine>=0 -> 1024 bins), then select
  hs[tid] = 0;
  __syncthreads();
  for (int base = 0; base < P; base += 4096) {
    int i0 = base + tid;
    int i1 = i0 + 1024, i2 = i0 + 2048, i3 = i0 + 3072;
    unsigned b0 = (i0 < P) ? __float_as_uint(mrow[i0]) : 0xFFFFFFFFu;
    unsigned b1 = (i1 < P) ? __float_as_uint(mrow[i1]) : 0xFFFFFFFFu;
    unsigned b2 = (i2 < P) ? __float_as_uint(mrow[i2]) : 0xFFFFFFFFu;
    unsigned b3 = (i3 < P) ? __float_as_uint(mrow[i3]) : 0xFFFFFFFFu;
    if (b0 != 0xFFFFFFFFu) atomicAdd(&hs[b0 >> 21], 1u);
    if (b1 != 0xFFFFFFFFu) atomicAdd(&hs[b1 >> 21], 1u);
    if (b2 != 0xFFFFFFFFu) atomicAdd(&hs[b2 >> 21], 1u);
    if (b3 != 0xFFFFFFFFu) atomicAdd(&hs[b3 >> 21], 1u);
  }
  __syncthreads();
  {
    S[tid] = hs[tid];
    __syncthreads();
    for (int off = 1; off < 1024; off <<= 1) {
      unsigned add = (tid + off < 1024) ? S[tid + off] : 0;
      __syncthreads();
      S[tid] += add;
      __syncthreads();
    }
    int cnt = __syncthreads_count((long long)S[tid] >= k);
    int seg = cnt - 1;
    if (tid == seg) {
      long long cum = (seg + 1 < 1024) ? (long long)S[seg + 1] : 0;
      spf1 = seg;
      sk1 = (int)(k - cum);
    }
  }
  __syncthreads();
  int pf = spf1;

  // pass A: bits[20:10] within top bin (2048 bins)
  hs[tid] = 0; hs[tid + 1024] = 0;
  __syncthreads();
  for (int base = 0; base < P; base += 4096) {
    int i0 = base + tid;
    int i1 = i0 + 1024, i2 = i0 + 2048, i3 = i0 + 3072;
    unsigned b0 = (i0 < P) ? __float_as_uint(mrow[i0]) : 0u;
    unsigned b1 = (i1 < P) ? __float_as_uint(mrow[i1]) : 0u;
    unsigned b2 = (i2 < P) ? __float_as_uint(mrow[i2]) : 0u;
    unsigned b3 = (i3 < P) ? __float_as_uint(mrow[i3]) : 0u;
    if (i0 < P && (int)(b0 >> 21) == pf) atomicAdd(&hs[(b0 >> 10) & 2047], 1u);
    if (i1 < P && (int)(b1 >> 21) == pf) atomicAdd(&hs[(b1 >> 10) & 2047], 1u);
    if (i2 < P && (int)(b2 >> 21) == pf) atomicAdd(&hs[(b2 >> 10) & 2047], 1u);
    if (i3 < P && (int)(b3 >> 21) == pf) atomicAdd(&hs[(b3 >> 10) & 2047], 1u);
  }
  __syncthreads();
  {
    unsigned h0 = hs[tid * 2], h1v = hs[tid * 2 + 1];
    S[tid] = h0 + h1v;
    __syncthreads();
    for (int off = 1; off < 1024; off <<= 1) {
      unsigned add = (tid + off < 1024) ? S[tid + off] : 0;
      __syncthreads();
      S[tid] += add;
      __syncthreads();
    }
    long long kk = (long long)sk1;
    int cnt = __syncthreads_count((long long)S[tid] >= kk);
    int seg = cnt - 1;
    if (tid == seg) {
      long long cum = (seg + 1 < 1024) ? (long long)S[seg + 1] : 0;
      int bin = seg * 2;
      if (cum + h1v >= kk) bin = seg * 2 + 1;
      else cum += h1v;
      spf21 = (pf << 11) | bin;
      sk2 = (int)(kk - cum);
    }
  }
  __syncthreads();
  int pf21 = spf21;

  // pass B: bits[9:0] (1024 bins)
  hs[tid] = 0;
  __syncthreads();
  for (int base = 0; base < P; base += 4096) {
    int i0 = base + tid;
    int i1 = i0 + 1024, i2 = i0 + 2048, i3 = i0 + 3072;
    unsigned b0 = (i0 < P) ? __float_as_uint(mrow[i0]) : 0u;
    unsigned b1 = (i1 < P) ? __float_as_uint(mrow[i1]) : 0u;
    unsigned b2 = (i2 < P) ? __float_as_uint(mrow[i2]) : 0u;
    unsigned b3 = (i3 < P) ? __float_as_uint(mrow[i3]) : 0u;
    if (i0 < P && (int)(b0 >> 10) == pf21) atomicAdd(&hs[b0 & 1023], 1u);
    if (i1 < P && (int)(b1 >> 10) == pf21) atomicAdd(&hs[b1 & 1023], 1u);
    if (i2 < P && (int)(b2 >> 10) == pf21) atomicAdd(&hs[b2 & 1023], 1u);
    if (i3 < P && (int)(b3 >> 10) == pf21) atomicAdd(&hs[b3 & 1023], 1u);
  }
  __syncthreads();
  {
    S[tid] = hs[tid];
    __syncthreads();
    for (int off = 1; off < 1024; off <<= 1) {
      unsigned add = (tid + off < 1024) ? S[tid + off] : 0;
      __syncthreads();
      S[tid] += add;
      __syncthreads();
    }
    long long kk = (long long)sk2;
    int cnt = __syncthreads_count((long long)S[tid] >= kk);
    int seg = cnt - 1;
    if (tid == seg) {
      long long cum = (seg + 1 < 1024) ? (long long)S[seg + 1] : 0;
      unsigned tb = ((unsigned)pf21 << 10) | (unsigned)seg;
      stb = tb;
      stie = (double)(kk - cum) * (double)__uint_as_float(tb);
    }
  }
  __syncthreads();

  unsigned tb = stb;
  double v = 0.0;
  for (int base = 0; base < P; base += 4096) {
    int i0 = base + tid;
    int i1 = i0 + 1024, i2 = i0 + 2048, i3 = i0 + 3072;
    unsigned b0 = (i0 < P) ? __float_as_uint(mrow[i0]) : 0u;
    unsigned b1 = (i1 < P) ? __float_as_uint(mrow[i1]) : 0u;
    unsigned b2 = (i2 < P) ? __float_as_uint(mrow[i2]) : 0u;
    unsigned b3 = (i3 < P) ? __float_as_uint(mrow[i3]) : 0u;
    if (b0 > tb) v += (double)__uint_as_float(b0);
    if (b1 > tb) v += (double)__uint_as_float(b1);
    if (b2 > tb) v += (double)__uint_as_float(b2);
    if (b3 > tb) v += (double)__uint_as_float(b3);
  }
  v = dwave(v);
  if (lane == 0) rs[wid] = v;
  __syncthreads();
  if (tid == 0) {
    double t = 0;
    for (int i = 0; i < 16; ++i) t += rs[i];
    pfs_b[b] = t + stie;
  }
}

__global__ void k_fin(const double* __restrict__ pllb,
                      const double* __restrict__ pllmb,
                      const double* __restrict__ plcb,
                      const double* __restrict__ pfs_b,
                      const int* __restrict__ num_pos, float* __restrict__ out,
                      int B) {
  if (threadIdx.x == 0) {
    double A = 0, C = 0, D = 0, F = 0, N = 0;
    for (int i = 0; i < B; ++i) {
      A += pllb[i]; C += pllmb[i]; D += pfs_b[i] * 0.0 + plcb[i]; F += pfs_b[i];
      N += (double)num_pos[i];
    }
    if (N < 1.0) N = 1.0;
    out[0] = (float)(A / N);
    out[1] = (float)((D + F) / N);
    out[2] = (float)(C / N);
  }
}

extern "C" void kernel_launch(void* const* d_in, const int* in_sizes, int n_in,
                              void* d_out, int out_size, void* d_ws,
                              size_t ws_size, hipStream_t stream) {
  const float* loc = (const float*)d_in[0];
  const float* conf = (const float*)d_in[1];
  const float* lm = (const float*)d_in[2];
  const float* priors = (const float*)d_in[3];
  const float* targets = (const float*)d_in[4];

  int P = in_sizes[3] / 4;
  int B = in_sizes[0] / (4 * P);
  int G = in_sizes[4] / (15 * B);
  int PTI = (P + 256 * PPI - 1) / (256 * PPI);
  int NIOU = B * PTI;
  int NGC = (G + GC - 1) / GC;
  int PC = 8;
  int NBP = B * NGC * PC;

  char* w = (char*)d_ws;
  size_t off = 0;
  // ---- zeroed region: bp only ----
  unsigned long long* bp = (unsigned long long*)(w + off);
  off += (size_t)B * G * 8;
  size_t clear_bytes = off;
  // ---- non-zeroed (written unconditionally every call) ----
  off = (off + 255) & ~(size_t)255;
  float* bto = (float*)(w + off);
  off += (size_t)B * P * 4;
  int* bti = (int*)(w + off);
  off += (size_t)B * P * 4;
  float* mine = (float*)(w + off);
  off += (size_t)B * P * 4;
  double* pll = (double*)(w + off);
  off += (size_t)NIOU * 8;
  double* pllm = (double*)(w + off);
  off += (size_t)NIOU * 8;
  double* plc = (double*)(w + off);
  off += (size_t)NIOU * 8;
  double* msum = (double*)(w + off);
  off += (size_t)NIOU * 8;
  int* pnp = (int*)(w + off);
  off += (size_t)NIOU * 4;
  off = (off + 7) & ~(size_t)7;
  double* dacc = (double*)(w + off);
  off += (size_t)B * 4 * 8;
  double* pllb = (double*)(w + off);
  off += (size_t)B * 8;
  double* pllmb = (double*)(w + off);
  off += (size_t)B * 8;
  double* plcb = (double*)(w + off);
  off += (size_t)B * 8;
  double* pfs_b = (double*)(w + off);
  off += (size_t)B * 8;
  int* dnpb = (int*)(w + off);
  off += (size_t)B * 4;
  int* anyv = (int*)(w + off);
  off += (size_t)B * 4;
  int* num_pos = (int*)(w + off);
  off += (size_t)B * 4;

  hipMemsetAsync(d_ws, 0, clear_bytes, stream);

  k_mm<<<NIOU + NBP, 256, 0, stream>>>(priors, targets, loc, conf, lm, bto,
                                       bti, bp, mine, pll, pllm, plc, msum,
                                       pnp, P, G, NIOU, PTI, NGC, PC);
  k_fix<<<B, G, 0, stream>>>(bp, bto, bti, conf, loc, lm, priors, targets,
                             mine, anyv, dacc, dnpb, P, G);
  k_tail<<<B, 1024, 0, stream>>>(pnp, msum, pll, pllm, plc, dacc, dnpb, anyv,
                                 mine, num_pos, pllb, pllmb, plcb, pfs_b, P,
                                 PTI);
  k_fin<<<1, 64, 0, stream>>>(pllb, pllmb, plcb, pfs_b, num_pos,
                              (float*)d_out, B);
}